// Round 8
// baseline (218.097 us; speedup 1.0000x reference)
//
#include <hip/hip_runtime.h>
#include <math.h>
#include <stdint.h>

// Problem constants (B=1)
static constexpr int T   = 2048;
static constexpr int D   = 2048;
static constexpr int HQ  = 32;
static constexpr int HKV = 8;
static constexpr int DH  = 64;
static constexpr int DKV = HKV * DH;       // 512
static constexpr int NQKV = D + 2 * DKV;   // 3072 fused QKV output width

typedef float f32x4 __attribute__((ext_vector_type(4)));
typedef __bf16 bf16x8 __attribute__((ext_vector_type(8)));
typedef __bf16 bf16x2 __attribute__((ext_vector_type(2)));
typedef unsigned short u16x8 __attribute__((ext_vector_type(8)));
typedef unsigned short u16x4 __attribute__((ext_vector_type(4)));

__device__ __forceinline__ unsigned short f2bf(float f) {
  union { float f; unsigned u; } v; v.f = f;
  unsigned u = v.u;
  return (unsigned short)((u + 0x7FFFu + ((u >> 16) & 1u)) >> 16);  // RNE
}
__device__ __forceinline__ float bf2f(unsigned short b) {
  union { unsigned u; float f; } v; v.u = ((unsigned)b) << 16;
  return v.f;
}
// packed f32x2 -> bf16x2 (single v_cvt_pk_bf16_f32 on gfx950)
__device__ __forceinline__ unsigned pk2bf(float a, float b) {
#if __has_builtin(__builtin_amdgcn_cvt_pk_bf16_f32)
  bf16x2 r = __builtin_amdgcn_cvt_pk_bf16_f32(a, b);
  return __builtin_bit_cast(unsigned, r);
#else
  return (unsigned)f2bf(a) | ((unsigned)f2bf(b) << 16);
#endif
}
__device__ __forceinline__ float fexp2(float x) {
#if __has_builtin(__builtin_amdgcn_exp2f)
  return __builtin_amdgcn_exp2f(x);  // raw v_exp_f32 (base-2)
#else
  return exp2f(x);
#endif
}
__device__ __forceinline__ float frcp(float x) {
#if __has_builtin(__builtin_amdgcn_rcpf)
  return __builtin_amdgcn_rcpf(x);   // v_rcp_f32, ~1ulp — fine for bf16 output
#else
  return 1.0f / x;
#endif
}
__device__ __forceinline__ f32x4 mfma16(u16x8 a, u16x8 b, f32x4 c) {
  return __builtin_amdgcn_mfma_f32_16x16x32_bf16(
      __builtin_bit_cast(bf16x8, a), __builtin_bit_cast(bf16x8, b), c, 0, 0, 0);
}
// async global->LDS, 16B per lane. LDS dest is wave-uniform base + lane*16.
__device__ __forceinline__ void gld16(const unsigned short* g, unsigned short* l) {
  __builtin_amdgcn_global_load_lds(
      (const __attribute__((address_space(1))) unsigned*)g,
      (__attribute__((address_space(3))) unsigned*)l, 16, 0, 0);
}

// --------------------------------------------- fused fp32 -> bf16 for all inputs
// One launch converts x, Wq, Wk, Wv, Wo. Segments in units of 2048-element
// blocks (256 thr x 8): x 2048 | Wq 2048 | Wk 512 | Wv 512 | Wo 2048 = 7168.
__global__ __launch_bounds__(256) void cvt_all(const float* __restrict__ x,
                                               const float* __restrict__ Wq,
                                               const float* __restrict__ Wk,
                                               const float* __restrict__ Wv,
                                               const float* __restrict__ Wo,
                                               unsigned short* __restrict__ xb,
                                               unsigned short* __restrict__ wqkv,
                                               unsigned short* __restrict__ wob) {
  int b = blockIdx.x;
  const float* src;
  unsigned short* dst;
  if (b < 2048)      { src = x;  dst = xb; }
  else if (b < 4096) { src = Wq; dst = wqkv;                          b -= 2048; }
  else if (b < 4608) { src = Wk; dst = wqkv + (size_t)D * D;          b -= 4096; }
  else if (b < 5120) { src = Wv; dst = wqkv + (size_t)(D + DKV) * D;  b -= 4608; }
  else               { src = Wo; dst = wob;                           b -= 5120; }
  size_t i = ((size_t)b * 256 + threadIdx.x) * 8;
  float4 a = *(const float4*)(src + i);
  float4 c = *(const float4*)(src + i + 4);
  uint4 r = {pk2bf(a.x, a.y), pk2bf(a.z, a.w), pk2bf(c.x, c.y), pk2bf(c.z, c.w)};
  *(uint4*)(dst + i) = r;
}

// ---------------------------------------------------- C[M,N] = A[M,K] @ Bt[N,K]^T
// 64M x 128N block tile, BK=128, two-barrier K-loop, gld16 XOR-swizzle staging.
// EPI=0: fp32 C store (out-projection).
// EPI=1: fused QKV epilogue — Q/K blocks get RoPE applied on the fp32 acc
//   (pair = adjacent cols = lanes c, c^1 -> one shfl_xor each; cos/sin gathers
//   from the 256KB L1-resident tables), Q additionally scaled by log2e/8 for
//   the exp2-domain attention; V blocks store plain bf16 (transposed later).
//   Uniform per-block branch: bn<2048 Q | bn<2560 K | else V.
template <int EPI>
__global__ __launch_bounds__(256) void gemm_bt_bf16(const unsigned short* __restrict__ A,
                                                    const unsigned short* __restrict__ Bt,
                                                    void* __restrict__ Cv,
                                                    int N, int K,
                                                    const float* __restrict__ cosb,
                                                    const float* __restrict__ sinb) {
  __shared__ alignas(16) unsigned short As[64 * 128];   // 16 KB
  __shared__ alignas(16) unsigned short Bs[128 * 128];  // 32 KB

  const int bn = blockIdx.x * 128, bm = blockIdx.y * 64;
  const int tid = threadIdx.x, w = tid >> 6, lane = tid & 63;
  const int c = lane & 15, quad = lane >> 4;

  const int r4 = lane >> 4, ch = lane & 15;
  const unsigned short* aRow = A + (size_t)(bm + w * 16 + r4) * K;
  const unsigned short* bRow = Bt + (size_t)(bn + w * 32 + r4) * K;
  unsigned short* AsW = As + (w * 16) * 128;
  unsigned short* BsW = Bs + (w * 32) * 128;

  f32x4 acc[4][2] = {};

  for (int k0 = 0; k0 < K; k0 += 128) {
#pragma unroll
    for (int j = 0; j < 4; j++) {
      const int sch = ch ^ ((j * 4 + r4) & 15);
      gld16(aRow + (size_t)(j * 4) * K + k0 + sch * 8, AsW + j * 4 * 128);
    }
#pragma unroll
    for (int j = 0; j < 8; j++) {
      const int sch = ch ^ ((j * 4 + r4) & 15);
      gld16(bRow + (size_t)(j * 4) * K + k0 + sch * 8, BsW + j * 4 * 128);
    }
    __syncthreads();  // drain vmcnt -> tiles complete

#pragma unroll
    for (int ks = 0; ks < 4; ks++) {
      const int slot = (ks * 4 + quad) ^ c;
      u16x8 a[4], b[2];
#pragma unroll
      for (int mi = 0; mi < 4; mi++)
        a[mi] = *(const u16x8*)&As[(mi * 16 + c) * 128 + slot * 8];
#pragma unroll
      for (int ni = 0; ni < 2; ni++)
        b[ni] = *(const u16x8*)&Bs[(w * 32 + ni * 16 + c) * 128 + slot * 8];
#pragma unroll
      for (int mi = 0; mi < 4; mi++)
#pragma unroll
        for (int ni = 0; ni < 2; ni++)
          acc[mi][ni] = mfma16(a[mi], b[ni], acc[mi][ni]);
    }
    __syncthreads();  // protect LDS from next-iter overwrite
  }

  if (EPI == 0) {
#pragma unroll
    for (int mi = 0; mi < 4; mi++)
#pragma unroll
      for (int ni = 0; ni < 2; ni++)
#pragma unroll
        for (int r = 0; r < 4; r++) {
          size_t row = (size_t)(bm + mi * 16 + quad * 4 + r);
          size_t col = (size_t)(bn + w * 32 + ni * 16 + c);
          ((float*)Cv)[row * N + col] = acc[mi][ni][r];
        }
  } else if (bn < 2560) {
    // Q or K block: RoPE on fp32 acc. Pair (x0,x1) = (even col, odd col) =
    // lanes (c, c^1), same (mi,ni,r), same freq index i = ((col&63)>>1).
    // even lane: o0 = x0*cs - x1*sn ; odd lane: o1 = x0*sn + x1*cs
    //   -> out = val*cs + sgn*px*sn, sgn = (c&1) ? +1 : -1.
    const float sc = (bn < 2048) ? 0.125f * 1.44269504088896340736f : 1.0f;
    const float sgn = (c & 1) ? 1.0f : -1.0f;
#pragma unroll
    for (int mi = 0; mi < 4; mi++)
#pragma unroll
      for (int ni = 0; ni < 2; ni++) {
        const int i = ((w * 32 + ni * 16 + c) & 63) >> 1;  // bn%64==0
#pragma unroll
        for (int r = 0; r < 4; r++) {
          const int t = bm + mi * 16 + quad * 4 + r;
          const float cs = cosb[t * 32 + i];
          const float sn = sinb[t * 32 + i];
          const float val = acc[mi][ni][r];
          const float px = __shfl_xor(val, 1, 64);
          const float outv = (val * cs + sgn * px * sn) * sc;
          ((unsigned short*)Cv)[(size_t)t * N + bn + w * 32 + ni * 16 + c] = f2bf(outv);
        }
      }
  } else {
    // V block: plain bf16 store (transposed to VT by vt_only afterwards)
#pragma unroll
    for (int mi = 0; mi < 4; mi++)
#pragma unroll
      for (int ni = 0; ni < 2; ni++)
#pragma unroll
        for (int r = 0; r < 4; r++) {
          size_t row = (size_t)(bm + mi * 16 + quad * 4 + r);
          size_t col = (size_t)(bn + w * 32 + ni * 16 + c);
          ((unsigned short*)Cv)[row * N + col] = f2bf(acc[mi][ni][r]);
        }
  }
}

// ----------------------------------------- V transpose only (rope now in GEMM)
// 256 blocks: 64x64 transpose of V (T,dkv)->(dkv,T), pad-65 LDS, conflict-free.
__global__ __launch_bounds__(256) void vt_only(const unsigned short* __restrict__ QKV,
                                               unsigned short* __restrict__ VT) {
  __shared__ unsigned short Ts[64][65];
  const int bid = blockIdx.x;
  const int tb = bid & 31, db = bid >> 5;   // tb: T/64, db: DKV/64
  const int tid = threadIdx.x;
  const int r = tid >> 2, c0 = (tid & 3) * 16;
  const unsigned short* src = QKV + (size_t)(tb * 64 + r) * NQKV + (D + DKV) + db * 64 + c0;
  *(u16x8*)&Ts[r][c0]     = *(const u16x8*)src;
  *(u16x8*)&Ts[r][c0 + 8] = *(const u16x8*)(src + 8);
  __syncthreads();
  u16x8 a, b;
#pragma unroll
  for (int j = 0; j < 8; j++) a[j] = Ts[c0 + j][r];
#pragma unroll
  for (int j = 0; j < 8; j++) b[j] = Ts[c0 + 8 + j][r];
  unsigned short* dst = VT + (size_t)(db * 64 + r) * T + tb * 64 + c0;
  *(u16x8*)dst = a;
  *(u16x8*)(dst + 8) = b;
}

// ------------------------------------------------------------------- attention
// v8: v1's inner loop per-wave, but 8 WAVES per block (512 thr) sharing one
// K/V stage: waves 0-3 = q-subtile A (rows qbase..+15) x 4 heads, waves 4-7 =
// subtile B (rows qbase+16..+31) x 4 heads. Same per-wave register/code shape
// as v1 (68 VGPR class), but staging traffic + barriers per unit MFMA are
// HALVED and waves/CU rise 12 -> 16 (2 blocks x 8 waves; v4's 2x4=8 was the
// regression). LDS 50,432 B (Kt 16K dbuf + Vt 16K dbuf + Pb 18K). Grid
// 8 x 64 = 512 blocks; bid%8 = kh keeps per-XCD K/V L2 affinity. Folded
// y-map (v4b corrected, correctness-proven): same-CU block pairs sum to
// ~constant work. nFull = qt2>>1 is exact for both subtiles.
// No setprio (v6: measured -8% here). No direct-global K/V/P (v2/v3/v5).
__global__ __launch_bounds__(512, 4) void attn_kernel(const unsigned short* __restrict__ QKV,
                                                      const unsigned short* __restrict__ VT,
                                                      unsigned short* __restrict__ Ob) {
  const int kh = blockIdx.x;                          // kv head 0..7
  const int ny = (int)gridDim.y;                      // 64
  const int y = (int)blockIdx.y;
  // folded: y<32 -> qt2 = 63,61,...,1 (long); y>=32 -> qt2 = 0,2,...,62
  const int qt2 = (y < (ny >> 1)) ? (ny - 1 - 2 * y) : (2 * (y - (ny >> 1)));
  const int qbase = qt2 * 32;
  const int tid = threadIdx.x, w = tid >> 6, lane = tid & 63;
  const int c = lane & 15, quad = lane >> 4;
  const int h = kh * 4 + (w & 3);                     // this wave's q head
  const int sub = w >> 2;                             // q-subtile 0/1
  const int qbaseW = qbase + sub * 16;                // this wave's q rows

  __shared__ alignas(16) unsigned short Kt[2][64 * 64];   // (key, dh) swizzled, 2x8 KB
  __shared__ alignas(16) unsigned short Vt[2][64 * 64];   // (dh, key) swizzled, 2x8 KB
  __shared__ alignas(16) unsigned short Pb[8 * 16 * 72];  // per-wave P (q, key), 18 KB

  unsigned short* PbW = Pb + w * 16 * 72;

  // Q as B-fragments: q-row qbaseW+c, head h (pre-scaled by log2e/8 in GEMM epi)
  u16x8 qf[2];
  {
    const unsigned short* qp = QKV + (size_t)(qbaseW + c) * NQKV + h * DH + quad * 8;
    qf[0] = *(const u16x8*)qp;
    qf[1] = *(const u16x8*)(qp + 32);
  }

  // staging: wave w stages rows [w*8, w*8+8) of Kt and Vt; ONE gld16 each.
  // lane -> (srow = lane>>3, chunk = lane&7); source chunk XOR-swizzled by row.
  const int srow = lane >> 3;
  const int sch  = (lane & 7) ^ srow;
  const unsigned short* kgBase = QKV + D + (size_t)(w * 8 + srow) * NQKV + kh * DH + sch * 8;
  const unsigned short* vgBase = VT + (size_t)(kh * DH + w * 8 + srow) * T + sch * 8;

  f32x4 o[4] = {};
  float l = 0.f;   // per-lane partial softmax denominator (reduced at the end)

  const int nFull = qt2 >> 1;  // diagonal key-tile index (same for both subtiles)

  // prologue: stage tile 0 into buffer 0
  gld16(kgBase, &Kt[0][(w * 8) * 64]);
  gld16(vgBase, &Vt[0][(w * 8) * 64]);

  for (int st = 0; st <= nFull; st++) {
    const int cur = st & 1;
    __syncthreads();  // drains cur-buffer loads; all waves done with other buf
    if (st < nFull) {
      gld16(kgBase + (size_t)(st + 1) * 64 * NQKV, &Kt[cur ^ 1][(w * 8) * 64]);
      gld16(vgBase + (size_t)(st + 1) * 64,        &Vt[cur ^ 1][(w * 8) * 64]);
    }

    // S^T = K Q^T : A-frag = K rows, B-frag = Q. D[key=ni*16+quad*4+r][q=c].
    f32x4 sacc[4] = {};
#pragma unroll
    for (int ks = 0; ks < 2; ks++) {
#pragma unroll
      for (int ni = 0; ni < 4; ni++) {
        const int slot = (ks * 4 + quad) ^ (c & 7);
        u16x8 kf = *(const u16x8*)&Kt[cur][(ni * 16 + c) * 64 + slot * 8];
        sacc[ni] = mfma16(kf, qf[ks], sacc[ni]);
      }
    }

    // causal mask: only diagonal tile (uniform branch; per-wave q rows)
    if (st == nFull) {
      const int qrow = qbaseW + c;
#pragma unroll
      for (int ni = 0; ni < 4; ni++)
#pragma unroll
        for (int r = 0; r < 4; r++) {
          int key = st * 64 + ni * 16 + quad * 4 + r;
          if (key > qrow) sacc[ni][r] = -INFINITY;
        }
    }

    // p = exp2(s) directly (no max subtraction — scores bounded), pack to LDS.
#pragma unroll
    for (int ni = 0; ni < 4; ni++) {
      float p0 = fexp2(sacc[ni][0]);
      float p1 = fexp2(sacc[ni][1]);
      float p2 = fexp2(sacc[ni][2]);
      float p3 = fexp2(sacc[ni][3]);
      l += (p0 + p1) + (p2 + p3);
      uint2 pr = {pk2bf(p0, p1), pk2bf(p2, p3)};
      // P^T (C-layout) -> P (q,key) rows: lane writes row c
      *(uint2*)&PbW[c * 72 + ni * 16 + quad * 4] = pr;
    }

    // O += P V : A-frag = P rows (own-wave LDS region), B-frag = V^T rows.
#pragma unroll
    for (int ks = 0; ks < 2; ks++) {
      u16x8 pf = *(const u16x8*)&PbW[c * 72 + ks * 32 + quad * 8];
#pragma unroll
      for (int ni = 0; ni < 4; ni++) {
        const int slot = (ks * 4 + quad) ^ (c & 7);
        u16x8 vf = *(const u16x8*)&Vt[cur][(ni * 16 + c) * 64 + slot * 8];
        o[ni] = mfma16(pf, vf, o[ni]);
      }
    }
  }

  // reduce l across the 4 quads sharing each q-row (lanes differ in bits 4-5)
  l += __shfl_xor(l, 16, 64);
  l += __shfl_xor(l, 32, 64);

  float lR[4];
#pragma unroll
  for (int r = 0; r < 4; r++) lR[r] = frcp(__shfl(l, quad * 4 + r, 64));
#pragma unroll
  for (int ni = 0; ni < 4; ni++)
#pragma unroll
    for (int r = 0; r < 4; r++) {
      size_t row = (size_t)(qbaseW + quad * 4 + r);
      size_t col = (size_t)(h * DH + ni * 16 + c);
      Ob[row * D + col] = f2bf(o[ni][r] * lR[r]);
    }
}

// ------------------------------------------------------------------- launcher
extern "C" void kernel_launch(void* const* d_in, const int* in_sizes, int n_in,
                              void* d_out, int out_size, void* d_ws, size_t ws_size,
                              hipStream_t stream) {
  const float* x  = (const float*)d_in[0];
  const float* Wq = (const float*)d_in[1];
  const float* Wk = (const float*)d_in[2];
  const float* Wv = (const float*)d_in[3];
  const float* Wo = (const float*)d_in[4];
  const float* rc = (const float*)d_in[5];
  const float* rs = (const float*)d_in[6];
  float* out = (float*)d_out;

  char* ws = (char*)d_ws;
  // bf16 workspace (bytes):
  //   xb    [0,8M)    x bf16; dead after QKV GEMM -> aliased by Ab
  //   wqkv  [8,20M)   fused QKV weights; dead after QKV GEMM -> VT reuses [8,10M)
  //   wob   [20,28M)
  //   qkvb  [28,40M)
  unsigned short* xb   = (unsigned short*)(ws);
  unsigned short* wqkv = (unsigned short*)(ws + (size_t)(8u  << 20));
  unsigned short* wob  = (unsigned short*)(ws + (size_t)(20u << 20));
  unsigned short* qkvb = (unsigned short*)(ws + (size_t)(28u << 20));
  unsigned short* Ab   = xb;                    // alias (x dead)
  unsigned short* VT   = wqkv;                  // alias (wqkv dead after GEMM), 2 MB

  // 1) all fp32->bf16 conversions in one launch
  cvt_all<<<dim3(7168), 256, 0, stream>>>(x, Wq, Wk, Wv, Wo, xb, wqkv, wob);

  // 2) fused QKV projection + RoPE epilogue (Q exp2-domain pre-scale included)
  gemm_bt_bf16<1><<<dim3(NQKV / 128, T / 64), 256, 0, stream>>>(xb, wqkv, qkvb,
                                                                NQKV, D, rc, rs);

  // 3) V^T materialization only (rope fused above): 256 blocks
  vt_only<<<dim3(256), 256, 0, stream>>>(qkvb, VT);

  // 4) attention: 8 kv-heads x 64 q-pair-tiles (folded) = 512 blocks, 8 waves
  attn_kernel<<<dim3(HKV, T / 32), 512, 0, stream>>>(qkvb, VT, Ab);

  // 5) output projection: (2048 x 2048) = Ab @ Wo^T, fp32 out. 16x32=512 = 2/CU
  gemm_bt_bf16<0><<<dim3(D / 128, T / 64), 256, 0, stream>>>(Ab, wob, out, D, D,
                                                             nullptr, nullptr);
}

// Round 9
// 213.375 us; speedup vs baseline: 1.0221x; 1.0221x over previous
//
#include <hip/hip_runtime.h>
#include <math.h>
#include <stdint.h>

// Problem constants (B=1)
static constexpr int T   = 2048;
static constexpr int D   = 2048;
static constexpr int HQ  = 32;
static constexpr int HKV = 8;
static constexpr int DH  = 64;
static constexpr int DKV = HKV * DH;       // 512
static constexpr int NQKV = D + 2 * DKV;   // 3072 fused QKV output width

typedef float f32x4 __attribute__((ext_vector_type(4)));
typedef __bf16 bf16x8 __attribute__((ext_vector_type(8)));
typedef __bf16 bf16x2 __attribute__((ext_vector_type(2)));
typedef unsigned short u16x8 __attribute__((ext_vector_type(8)));
typedef unsigned short u16x4 __attribute__((ext_vector_type(4)));

__device__ __forceinline__ unsigned short f2bf(float f) {
  union { float f; unsigned u; } v; v.f = f;
  unsigned u = v.u;
  return (unsigned short)((u + 0x7FFFu + ((u >> 16) & 1u)) >> 16);  // RNE
}
__device__ __forceinline__ float bf2f(unsigned short b) {
  union { unsigned u; float f; } v; v.u = ((unsigned)b) << 16;
  return v.f;
}
// packed f32x2 -> bf16x2 (single v_cvt_pk_bf16_f32 on gfx950)
__device__ __forceinline__ unsigned pk2bf(float a, float b) {
#if __has_builtin(__builtin_amdgcn_cvt_pk_bf16_f32)
  bf16x2 r = __builtin_amdgcn_cvt_pk_bf16_f32(a, b);
  return __builtin_bit_cast(unsigned, r);
#else
  return (unsigned)f2bf(a) | ((unsigned)f2bf(b) << 16);
#endif
}
__device__ __forceinline__ float fexp2(float x) {
#if __has_builtin(__builtin_amdgcn_exp2f)
  return __builtin_amdgcn_exp2f(x);  // raw v_exp_f32 (base-2)
#else
  return exp2f(x);
#endif
}
__device__ __forceinline__ float frcp(float x) {
#if __has_builtin(__builtin_amdgcn_rcpf)
  return __builtin_amdgcn_rcpf(x);   // v_rcp_f32, ~1ulp — fine for bf16 output
#else
  return 1.0f / x;
#endif
}
__device__ __forceinline__ f32x4 mfma16(u16x8 a, u16x8 b, f32x4 c) {
  return __builtin_amdgcn_mfma_f32_16x16x32_bf16(
      __builtin_bit_cast(bf16x8, a), __builtin_bit_cast(bf16x8, b), c, 0, 0, 0);
}
// async global->LDS, 16B per lane. LDS dest is wave-uniform base + lane*16.
__device__ __forceinline__ void gld16(const unsigned short* g, unsigned short* l) {
  __builtin_amdgcn_global_load_lds(
      (const __attribute__((address_space(1))) unsigned*)g,
      (__attribute__((address_space(3))) unsigned*)l, 16, 0, 0);
}

// --------------------------------------------- fused fp32 -> bf16 for all inputs
// One launch converts x, Wq, Wk, Wv, Wo. Segments in units of 2048-element
// blocks (256 thr x 8): x 2048 | Wq 2048 | Wk 512 | Wv 512 | Wo 2048 = 7168.
__global__ __launch_bounds__(256) void cvt_all(const float* __restrict__ x,
                                               const float* __restrict__ Wq,
                                               const float* __restrict__ Wk,
                                               const float* __restrict__ Wv,
                                               const float* __restrict__ Wo,
                                               unsigned short* __restrict__ xb,
                                               unsigned short* __restrict__ wqkv,
                                               unsigned short* __restrict__ wob) {
  int b = blockIdx.x;
  const float* src;
  unsigned short* dst;
  if (b < 2048)      { src = x;  dst = xb; }
  else if (b < 4096) { src = Wq; dst = wqkv;                          b -= 2048; }
  else if (b < 4608) { src = Wk; dst = wqkv + (size_t)D * D;          b -= 4096; }
  else if (b < 5120) { src = Wv; dst = wqkv + (size_t)(D + DKV) * D;  b -= 4608; }
  else               { src = Wo; dst = wob;                           b -= 5120; }
  size_t i = ((size_t)b * 256 + threadIdx.x) * 8;
  float4 a = *(const float4*)(src + i);
  float4 c = *(const float4*)(src + i + 4);
  uint4 r = {pk2bf(a.x, a.y), pk2bf(a.z, a.w), pk2bf(c.x, c.y), pk2bf(c.z, c.w)};
  *(uint4*)(dst + i) = r;
}

// ---------------------------------------------------- C[M,N] = A[M,K] @ Bt[N,K]^T
// 64M x 128N block tile, BK=128, two-barrier K-loop, gld16 XOR-swizzle staging.
// EPI=0: fp32 C store (out-projection).
// EPI=1: fused QKV epilogue — Q/K blocks get RoPE applied on the fp32 acc
//   (pair = adjacent cols = lanes c, c^1 -> one shfl_xor each; cos/sin gathers
//   from the 256KB L1-resident tables), Q additionally scaled by log2e/8 for
//   the exp2-domain attention; V blocks store plain bf16 (transposed later).
//   Uniform per-block branch: bn<2048 Q | bn<2560 K | else V.
template <int EPI>
__global__ __launch_bounds__(256) void gemm_bt_bf16(const unsigned short* __restrict__ A,
                                                    const unsigned short* __restrict__ Bt,
                                                    void* __restrict__ Cv,
                                                    int N, int K,
                                                    const float* __restrict__ cosb,
                                                    const float* __restrict__ sinb) {
  __shared__ alignas(16) unsigned short As[64 * 128];   // 16 KB
  __shared__ alignas(16) unsigned short Bs[128 * 128];  // 32 KB

  const int bn = blockIdx.x * 128, bm = blockIdx.y * 64;
  const int tid = threadIdx.x, w = tid >> 6, lane = tid & 63;
  const int c = lane & 15, quad = lane >> 4;

  const int r4 = lane >> 4, ch = lane & 15;
  const unsigned short* aRow = A + (size_t)(bm + w * 16 + r4) * K;
  const unsigned short* bRow = Bt + (size_t)(bn + w * 32 + r4) * K;
  unsigned short* AsW = As + (w * 16) * 128;
  unsigned short* BsW = Bs + (w * 32) * 128;

  f32x4 acc[4][2] = {};

  for (int k0 = 0; k0 < K; k0 += 128) {
#pragma unroll
    for (int j = 0; j < 4; j++) {
      const int sch = ch ^ ((j * 4 + r4) & 15);
      gld16(aRow + (size_t)(j * 4) * K + k0 + sch * 8, AsW + j * 4 * 128);
    }
#pragma unroll
    for (int j = 0; j < 8; j++) {
      const int sch = ch ^ ((j * 4 + r4) & 15);
      gld16(bRow + (size_t)(j * 4) * K + k0 + sch * 8, BsW + j * 4 * 128);
    }
    __syncthreads();  // drain vmcnt -> tiles complete

#pragma unroll
    for (int ks = 0; ks < 4; ks++) {
      const int slot = (ks * 4 + quad) ^ c;
      u16x8 a[4], b[2];
#pragma unroll
      for (int mi = 0; mi < 4; mi++)
        a[mi] = *(const u16x8*)&As[(mi * 16 + c) * 128 + slot * 8];
#pragma unroll
      for (int ni = 0; ni < 2; ni++)
        b[ni] = *(const u16x8*)&Bs[(w * 32 + ni * 16 + c) * 128 + slot * 8];
#pragma unroll
      for (int mi = 0; mi < 4; mi++)
#pragma unroll
        for (int ni = 0; ni < 2; ni++)
          acc[mi][ni] = mfma16(a[mi], b[ni], acc[mi][ni]);
    }
    __syncthreads();  // protect LDS from next-iter overwrite
  }

  if (EPI == 0) {
#pragma unroll
    for (int mi = 0; mi < 4; mi++)
#pragma unroll
      for (int ni = 0; ni < 2; ni++)
#pragma unroll
        for (int r = 0; r < 4; r++) {
          size_t row = (size_t)(bm + mi * 16 + quad * 4 + r);
          size_t col = (size_t)(bn + w * 32 + ni * 16 + c);
          ((float*)Cv)[row * N + col] = acc[mi][ni][r];
        }
  } else if (bn < 2560) {
    // Q or K block: RoPE on fp32 acc. Pair (x0,x1) = (even col, odd col) =
    // lanes (c, c^1), same (mi,ni,r), same freq index i = ((col&63)>>1).
    // even lane: o0 = x0*cs - x1*sn ; odd lane: o1 = x0*sn + x1*cs
    //   -> out = val*cs + sgn*px*sn, sgn = (c&1) ? +1 : -1.
    const float sc = (bn < 2048) ? 0.125f * 1.44269504088896340736f : 1.0f;
    const float sgn = (c & 1) ? 1.0f : -1.0f;
#pragma unroll
    for (int mi = 0; mi < 4; mi++)
#pragma unroll
      for (int ni = 0; ni < 2; ni++) {
        const int i = ((w * 32 + ni * 16 + c) & 63) >> 1;  // bn%64==0
#pragma unroll
        for (int r = 0; r < 4; r++) {
          const int t = bm + mi * 16 + quad * 4 + r;
          const float cs = cosb[t * 32 + i];
          const float sn = sinb[t * 32 + i];
          const float val = acc[mi][ni][r];
          const float px = __shfl_xor(val, 1, 64);
          const float outv = (val * cs + sgn * px * sn) * sc;
          ((unsigned short*)Cv)[(size_t)t * N + bn + w * 32 + ni * 16 + c] = f2bf(outv);
        }
      }
  } else {
    // V block: plain bf16 store (transposed to VT by vt_only afterwards)
#pragma unroll
    for (int mi = 0; mi < 4; mi++)
#pragma unroll
      for (int ni = 0; ni < 2; ni++)
#pragma unroll
        for (int r = 0; r < 4; r++) {
          size_t row = (size_t)(bm + mi * 16 + quad * 4 + r);
          size_t col = (size_t)(bn + w * 32 + ni * 16 + c);
          ((unsigned short*)Cv)[row * N + col] = f2bf(acc[mi][ni][r]);
        }
  }
}

// ----------------------------------------- V transpose only (rope now in GEMM)
// 256 blocks: 64x64 transpose of V (T,dkv)->(dkv,T), pad-65 LDS, conflict-free.
__global__ __launch_bounds__(256) void vt_only(const unsigned short* __restrict__ QKV,
                                               unsigned short* __restrict__ VT) {
  __shared__ unsigned short Ts[64][65];
  const int bid = blockIdx.x;
  const int tb = bid & 31, db = bid >> 5;   // tb: T/64, db: DKV/64
  const int tid = threadIdx.x;
  const int r = tid >> 2, c0 = (tid & 3) * 16;
  const unsigned short* src = QKV + (size_t)(tb * 64 + r) * NQKV + (D + DKV) + db * 64 + c0;
  *(u16x8*)&Ts[r][c0]     = *(const u16x8*)src;
  *(u16x8*)&Ts[r][c0 + 8] = *(const u16x8*)(src + 8);
  __syncthreads();
  u16x8 a, b;
#pragma unroll
  for (int j = 0; j < 8; j++) a[j] = Ts[c0 + j][r];
#pragma unroll
  for (int j = 0; j < 8; j++) b[j] = Ts[c0 + 8 + j][r];
  unsigned short* dst = VT + (size_t)(db * 64 + r) * T + tb * 64 + c0;
  *(u16x8*)dst = a;
  *(u16x8*)(dst + 8) = b;
}

// ------------------------------------------------------------------- attention
// v9: v1 loop structure VERBATIM (the only attn shape that ever measured
// 43 us; v2/v3/v4/v5/v6/v8 all regressed) with ONE change: the softmax/PV
// phase processes the 64 keys as two 32-key halves REUSING a half-size Pb
// (write half-P -> PV half, x2). Pb 9,216 -> 5,120 B; total LDS 41,984 ->
// 37,888 B, crossing the 40,960 threshold: 4 blocks/CU (was 3), all 1024
// blocks co-resident, no tail. Pb row stride 40 shorts (80 B) keeps pf
// ds_read_b128 16B-aligned (why v1 used 72); write-conflict class unchanged
// (~4-way). Half0-read -> half1-write WAR is same-wave in-order DS: no
// barrier. Half-1 exp2 overlaps half-0 PV MFMAs.
// No setprio (v6: -8%). No direct-global K/V/P (v2/v3/v5).
__global__ __launch_bounds__(256) void attn_kernel(const unsigned short* __restrict__ QKV,
                                                   const unsigned short* __restrict__ VT,
                                                   unsigned short* __restrict__ Ob) {
  const int kh = blockIdx.x;                          // kv head 0..7
  const int qt = (int)(gridDim.y - 1 - blockIdx.y);   // LPT: long tiles first
  const int qbase = qt * 16;
  const int tid = threadIdx.x, w = tid >> 6, lane = tid & 63;
  const int c = lane & 15, quad = lane >> 4;
  const int h = kh * 4 + w;                           // this wave's q head

  __shared__ alignas(16) unsigned short Kt[2][64 * 64];   // (key, dh) swizzled, 2x8 KB
  __shared__ alignas(16) unsigned short Vt[2][64 * 64];   // (dh, key) swizzled, 2x8 KB
  __shared__ alignas(16) unsigned short Pb[4 * 16 * 40];  // per-wave half-P, 5 KB

  unsigned short* PbW = Pb + w * 16 * 40;

  // Q as B-fragments: q-row qbase+c, head h (pre-scaled by log2e/8 in GEMM epi)
  u16x8 qf[2];
  {
    const unsigned short* qp = QKV + (size_t)(qbase + c) * NQKV + h * DH + quad * 8;
    qf[0] = *(const u16x8*)qp;
    qf[1] = *(const u16x8*)(qp + 32);
  }

  // staging: wave w stages rows [w*16, w*16+16) of Kt and Vt; 2 gld16 each.
  const int srow = lane >> 3;
  const int sch  = (lane & 7) ^ srow;
  const unsigned short* kgBase = QKV + D + (size_t)(w * 16 + srow) * NQKV + kh * DH + sch * 8;
  const unsigned short* vgBase = VT + (size_t)(kh * DH + w * 16 + srow) * T + sch * 8;

  f32x4 o[4] = {};
  float l = 0.f;   // per-lane partial softmax denominator (reduced at the end)

  const int nFull = qt >> 2;  // diagonal key-tile index

  // prologue: stage tile 0 into buffer 0
#pragma unroll
  for (int j = 0; j < 2; j++) {
    gld16(kgBase + (size_t)(j * 8) * NQKV, &Kt[0][(w * 16 + j * 8) * 64]);
    gld16(vgBase + (size_t)(j * 8) * T, &Vt[0][(w * 16 + j * 8) * 64]);
  }

  for (int st = 0; st <= nFull; st++) {
    const int cur = st & 1;
    __syncthreads();  // drains cur-buffer loads; all waves done with other buf
    if (st < nFull) {
#pragma unroll
      for (int j = 0; j < 2; j++) {
        gld16(kgBase + ((size_t)(st + 1) * 64 + (size_t)j * 8) * NQKV,
              &Kt[cur ^ 1][(w * 16 + j * 8) * 64]);
        gld16(vgBase + (size_t)(j * 8) * T + (st + 1) * 64,
              &Vt[cur ^ 1][(w * 16 + j * 8) * 64]);
      }
    }

    // S^T = K Q^T : A-frag = K rows, B-frag = Q. D[key=ni*16+quad*4+r][q=c].
    f32x4 sacc[4] = {};
#pragma unroll
    for (int ks = 0; ks < 2; ks++) {
#pragma unroll
      for (int ni = 0; ni < 4; ni++) {
        const int slot = (ks * 4 + quad) ^ (c & 7);
        u16x8 kf = *(const u16x8*)&Kt[cur][(ni * 16 + c) * 64 + slot * 8];
        sacc[ni] = mfma16(kf, qf[ks], sacc[ni]);
      }
    }

    // causal mask: only diagonal tile (uniform branch)
    if (st == nFull) {
      const int qrow = qbase + c;
#pragma unroll
      for (int ni = 0; ni < 4; ni++)
#pragma unroll
        for (int r = 0; r < 4; r++) {
          int key = st * 64 + ni * 16 + quad * 4 + r;
          if (key > qrow) sacc[ni][r] = -INFINITY;
        }
    }

    // softmax + PV in two 32-key halves sharing the half-size Pb:
    // half h2 covers keys 32*h2..32*h2+31 = sacc[2*h2], sacc[2*h2+1].
#pragma unroll
    for (int h2 = 0; h2 < 2; h2++) {
#pragma unroll
      for (int j = 0; j < 2; j++) {
        const int ni = h2 * 2 + j;
        float p0 = fexp2(sacc[ni][0]);
        float p1 = fexp2(sacc[ni][1]);
        float p2 = fexp2(sacc[ni][2]);
        float p3 = fexp2(sacc[ni][3]);
        l += (p0 + p1) + (p2 + p3);
        uint2 pr = {pk2bf(p0, p1), pk2bf(p2, p3)};
        // P^T (C-layout) -> P (q, key%32) rows: lane writes row c
        *(uint2*)&PbW[c * 40 + j * 16 + quad * 4] = pr;
      }
      // O += P V for this half: A-frag = P rows, B-frag = V^T rows.
      u16x8 pf = *(const u16x8*)&PbW[c * 40 + quad * 8];
#pragma unroll
      for (int ni = 0; ni < 4; ni++) {
        const int slot = (h2 * 4 + quad) ^ (c & 7);
        u16x8 vf = *(const u16x8*)&Vt[cur][(ni * 16 + c) * 64 + slot * 8];
        o[ni] = mfma16(pf, vf, o[ni]);
      }
    }
  }

  // reduce l across the 4 quads sharing each q-row (lanes differ in bits 4-5)
  l += __shfl_xor(l, 16, 64);
  l += __shfl_xor(l, 32, 64);

  float lR[4];
#pragma unroll
  for (int r = 0; r < 4; r++) lR[r] = frcp(__shfl(l, quad * 4 + r, 64));
#pragma unroll
  for (int ni = 0; ni < 4; ni++)
#pragma unroll
    for (int r = 0; r < 4; r++) {
      size_t row = (size_t)(qbase + quad * 4 + r);
      size_t col = (size_t)(h * DH + ni * 16 + c);
      Ob[row * D + col] = f2bf(o[ni][r] * lR[r]);
    }
}

// ------------------------------------------------------------------- launcher
extern "C" void kernel_launch(void* const* d_in, const int* in_sizes, int n_in,
                              void* d_out, int out_size, void* d_ws, size_t ws_size,
                              hipStream_t stream) {
  const float* x  = (const float*)d_in[0];
  const float* Wq = (const float*)d_in[1];
  const float* Wk = (const float*)d_in[2];
  const float* Wv = (const float*)d_in[3];
  const float* Wo = (const float*)d_in[4];
  const float* rc = (const float*)d_in[5];
  const float* rs = (const float*)d_in[6];
  float* out = (float*)d_out;

  char* ws = (char*)d_ws;
  // bf16 workspace (bytes):
  //   xb    [0,8M)    x bf16; dead after QKV GEMM -> aliased by Ab
  //   wqkv  [8,20M)   fused QKV weights; dead after QKV GEMM -> VT reuses [8,10M)
  //   wob   [20,28M)
  //   qkvb  [28,40M)
  unsigned short* xb   = (unsigned short*)(ws);
  unsigned short* wqkv = (unsigned short*)(ws + (size_t)(8u  << 20));
  unsigned short* wob  = (unsigned short*)(ws + (size_t)(20u << 20));
  unsigned short* qkvb = (unsigned short*)(ws + (size_t)(28u << 20));
  unsigned short* Ab   = xb;                    // alias (x dead)
  unsigned short* VT   = wqkv;                  // alias (wqkv dead after GEMM), 2 MB

  // 1) all fp32->bf16 conversions in one launch
  cvt_all<<<dim3(7168), 256, 0, stream>>>(x, Wq, Wk, Wv, Wo, xb, wqkv, wob);

  // 2) fused QKV projection + RoPE epilogue (Q exp2-domain pre-scale included)
  gemm_bt_bf16<1><<<dim3(NQKV / 128, T / 64), 256, 0, stream>>>(xb, wqkv, qkvb,
                                                                NQKV, D, rc, rs);

  // 3) V^T materialization only (rope fused above): 256 blocks
  vt_only<<<dim3(256), 256, 0, stream>>>(qkvb, VT);

  // 4) attention: 8 kv-heads x 128 q-tiles (LPT) = 1024 blocks, 4/CU resident
  attn_kernel<<<dim3(HKV, T / 16), 256, 0, stream>>>(qkvb, VT, Ab);

  // 5) output projection: (2048 x 2048) = Ab @ Wo^T, fp32 out. 16x32=512 = 2/CU
  gemm_bt_bf16<0><<<dim3(D / 128, T / 64), 256, 0, stream>>>(Ab, wob, out, D, D,
                                                             nullptr, nullptr);
}